// Round 1
// baseline (2806.231 us; speedup 1.0000x reference)
//
#include <hip/hip_runtime.h>

#define HIDDEN 16
#define N_FEAT 128
#define EMBED 128
#define N_GRAPHS 64

// ---- K2: in-degree histogram (real edges only; self-loop added as +1 later)
__global__ void k_deg(const int* __restrict__ dst, int n_edges, int* __restrict__ deg) {
    int e = blockIdx.x * blockDim.x + threadIdx.x;
    if (e < n_edges) atomicAdd(&deg[dst[e]], 1);
}

// ---- K3: h = x @ W1 ; dinv = rsqrt(deg+1) ; Hs = h * dinv
__global__ void k_gemm1(const float* __restrict__ x, const float* __restrict__ W1,
                        const int* __restrict__ deg, float* __restrict__ dinv,
                        float* __restrict__ Hs, int n) {
    __shared__ float Ws[N_FEAT * HIDDEN];   // 8 KB
    int tid = threadIdx.x;
    {   // 256 threads x 2 float4 = 512 float4 = 2048 floats
        const float4* w4 = (const float4*)W1;
        float4* s4 = (float4*)Ws;
        s4[tid * 2]     = w4[tid * 2];
        s4[tid * 2 + 1] = w4[tid * 2 + 1];
    }
    __syncthreads();
    int i = blockIdx.x * blockDim.x + tid;
    if (i >= n) return;

    float acc[HIDDEN];
#pragma unroll
    for (int o = 0; o < HIDDEN; o++) acc[o] = 0.f;

    const float4* xr = (const float4*)(x + (size_t)i * N_FEAT);
#pragma unroll 8
    for (int k4 = 0; k4 < N_FEAT / 4; k4++) {
        float4 xv = xr[k4];
        const float* w0 = &Ws[(k4 * 4 + 0) * HIDDEN];
        const float* w1 = &Ws[(k4 * 4 + 1) * HIDDEN];
        const float* w2 = &Ws[(k4 * 4 + 2) * HIDDEN];
        const float* w3 = &Ws[(k4 * 4 + 3) * HIDDEN];
#pragma unroll
        for (int o = 0; o < HIDDEN; o++)
            acc[o] += xv.x * w0[o] + xv.y * w1[o] + xv.z * w2[o] + xv.w * w3[o];
    }
    float di = rsqrtf((float)deg[i] + 1.0f);
    dinv[i] = di;
    float4* hout = (float4*)(Hs + (size_t)i * HIDDEN);
#pragma unroll
    for (int q = 0; q < 4; q++) {
        float4 v;
        v.x = acc[q * 4 + 0] * di; v.y = acc[q * 4 + 1] * di;
        v.z = acc[q * 4 + 2] * di; v.w = acc[q * 4 + 3] * di;
        hout[q] = v;
    }
}

// ---- K4/K6: P[dst] += V[src]  (16 floats per edge, f32 atomics)
__global__ void k_scatter(const int* __restrict__ src, const int* __restrict__ dst,
                          int n_edges, const float* __restrict__ V, float* __restrict__ P) {
    int e = blockIdx.x * blockDim.x + threadIdx.x;
    if (e >= n_edges) return;
    int s = src[e], d = dst[e];
    const float4* v4 = (const float4*)(V + (size_t)s * HIDDEN);
    float* p = P + (size_t)d * HIDDEN;
#pragma unroll
    for (int q = 0; q < 4; q++) {
        float4 v = v4[q];
        atomicAdd(&p[q * 4 + 0], v.x);
        atomicAdd(&p[q * 4 + 1], v.y);
        atomicAdd(&p[q * 4 + 2], v.z);
        atomicAdd(&p[q * 4 + 3], v.w);
    }
}

// ---- K5: Q = relu(dinv*(P + Hs) + b1) * dinv    (in-place: Q overwrites Hs)
__global__ void k_mid(const float* __restrict__ P, const float* __restrict__ dinv,
                      const float* __restrict__ b1, float* __restrict__ HsQ, int n) {
    int i = blockIdx.x * blockDim.x + threadIdx.x;
    if (i >= n) return;
    float di = dinv[i];
    float4* hq = (float4*)(HsQ + (size_t)i * HIDDEN);
    const float4* p4 = (const float4*)(P + (size_t)i * HIDDEN);
    const float4* b4 = (const float4*)b1;
#pragma unroll
    for (int q = 0; q < 4; q++) {
        float4 h = hq[q], p = p4[q], b = b4[q];
        float4 r;
        r.x = fmaxf(di * (p.x + h.x) + b.x, 0.f) * di;
        r.y = fmaxf(di * (p.y + h.y) + b.y, 0.f) * di;
        r.z = fmaxf(di * (p.z + h.z) + b.z, 0.f) * di;
        r.w = fmaxf(di * (p.w + h.w) + b.w, 0.f) * di;
        hq[q] = r;
    }
}

// ---- K7: r = dinv*(P2 + Q); S[batch] += r; cnt[batch] += 1 (sorted batch -> LDS buckets)
__global__ void k_pool(const float* __restrict__ P2, const float* __restrict__ Q,
                       const float* __restrict__ dinv, const int* __restrict__ batch,
                       float* __restrict__ S, float* __restrict__ cnt, int n) {
    __shared__ float ls[8][HIDDEN];
    __shared__ float lc[8];
    int tid = threadIdx.x;
    if (tid < 8) lc[tid] = 0.f;
    if (tid < 8 * HIDDEN) ((float*)ls)[tid] = 0.f;
    __syncthreads();

    int i0 = blockIdx.x * blockDim.x;
    int g0 = batch[i0 < n ? i0 : (n - 1)];   // wave-uniform (sorted batch)
    int i = i0 + tid;
    if (i < n) {
        int g = batch[i];
        float di = dinv[i];
        const float4* p4 = (const float4*)(P2 + (size_t)i * HIDDEN);
        const float4* q4 = (const float4*)(Q + (size_t)i * HIDDEN);
        float r[HIDDEN];
#pragma unroll
        for (int q = 0; q < 4; q++) {
            float4 p = p4[q], v = q4[q];
            r[q * 4 + 0] = di * (p.x + v.x);
            r[q * 4 + 1] = di * (p.y + v.y);
            r[q * 4 + 2] = di * (p.z + v.z);
            r[q * 4 + 3] = di * (p.w + v.w);
        }
        int off = g - g0;
        if (off >= 0 && off < 8) {
#pragma unroll
            for (int o = 0; o < HIDDEN; o++) atomicAdd(&ls[off][o], r[o]);
            atomicAdd(&lc[off], 1.f);
        } else {  // shouldn't happen with ~1500 nodes/graph, but stay correct
#pragma unroll
            for (int o = 0; o < HIDDEN; o++) atomicAdd(&S[(size_t)g * HIDDEN + o], r[o]);
            atomicAdd(&cnt[g], 1.f);
        }
    }
    __syncthreads();
    if (tid < 8 * HIDDEN) {
        int b = tid >> 4, o = tid & 15;
        int g = g0 + b;
        float v = ls[b][o];
        if (v != 0.f && g < N_GRAPHS) atomicAdd(&S[(size_t)g * HIDDEN + o], v);
    }
    if (tid < 8) {
        int g = g0 + tid;
        float c = lc[tid];
        if (c != 0.f && g < N_GRAPHS) atomicAdd(&cnt[g], c);
    }
}

// ---- K8: out[g][e] = (S[g]/cnt[g]) @ W2 + b2   (64 x 128)
__global__ void k_out(const float* __restrict__ S, const float* __restrict__ cnt,
                      const float* __restrict__ W2, const float* __restrict__ b2,
                      float* __restrict__ out) {
    int g = blockIdx.x;
    int e = threadIdx.x;
    float c = cnt[g];
    float acc = 0.f;
#pragma unroll
    for (int k = 0; k < HIDDEN; k++) acc += S[g * HIDDEN + k] * W2[k * EMBED + e];
    out[g * EMBED + e] = (c > 0.f) ? (acc / c + b2[e]) : 0.f;
}

extern "C" void kernel_launch(void* const* d_in, const int* in_sizes, int n_in,
                              void* d_out, int out_size, void* d_ws, size_t ws_size,
                              hipStream_t stream) {
    const float* x     = (const float*)d_in[0];
    const int*   ei    = (const int*)  d_in[1];
    const int*   batch = (const int*)  d_in[2];
    const float* W1    = (const float*)d_in[3];
    const float* b1    = (const float*)d_in[4];
    const float* W2    = (const float*)d_in[5];
    const float* b2    = (const float*)d_in[6];
    float* out = (float*)d_out;

    const int n       = in_sizes[2];
    const int n_edges = in_sizes[1] / 2;
    const int* src = ei;
    const int* dst = ei + n_edges;

    // workspace layout (all float-sized slots, 16B aligned)
    float* ws   = (float*)d_ws;
    float* Hs   = ws;                          // n*16  (Hs, later Q in-place)
    float* P    = Hs + (size_t)n * HIDDEN;     // n*16  (P1, re-zeroed for P2)
    float* dinv = P + (size_t)n * HIDDEN;      // n
    int*   deg  = (int*)(dinv + n);            // n
    float* S    = (float*)(deg + n);           // 64*16
    float* cnt  = S + N_GRAPHS * HIDDEN;       // 64

    hipMemsetAsync(deg, 0, (size_t)n * sizeof(int), stream);
    hipMemsetAsync(P, 0, (size_t)n * HIDDEN * sizeof(float), stream);
    hipMemsetAsync(S, 0, (N_GRAPHS * HIDDEN + N_GRAPHS) * sizeof(float), stream);

    const int eb = (n_edges + 255) / 256;
    const int nb = (n + 255) / 256;

    k_deg    <<<eb, 256, 0, stream>>>(dst, n_edges, deg);
    k_gemm1  <<<nb, 256, 0, stream>>>(x, W1, deg, dinv, Hs, n);
    k_scatter<<<eb, 256, 0, stream>>>(src, dst, n_edges, Hs, P);
    k_mid    <<<nb, 256, 0, stream>>>(P, dinv, b1, Hs, n);
    hipMemsetAsync(P, 0, (size_t)n * HIDDEN * sizeof(float), stream);
    k_scatter<<<eb, 256, 0, stream>>>(src, dst, n_edges, Hs, P);
    k_pool   <<<nb, 256, 0, stream>>>(P, Hs, dinv, batch, S, cnt, n);
    k_out    <<<N_GRAPHS, EMBED, 0, stream>>>(S, cnt, W2, b2, out);
}

// Round 2
// 433.343 us; speedup vs baseline: 6.4758x; 6.4758x over previous
//
#include <hip/hip_runtime.h>

#define HIDDEN 16
#define N_FEAT 128
#define EMBED 128
#define N_GRAPHS 64

// ---- in-degree histogram (real edges only; self-loop accounted as +1 later)
__global__ void k_deg(const int* __restrict__ dst, int n_edges, int* __restrict__ deg) {
    int e = blockIdx.x * blockDim.x + threadIdx.x;
    if (e < n_edges) atomicAdd(&deg[dst[e]], 1);
}

// ---- block sums of deg (scan level 1)
__global__ void k_bsum(const int* __restrict__ deg, int n, int* __restrict__ bsum) {
    __shared__ int s[256];
    int i = blockIdx.x * 256 + threadIdx.x;
    s[threadIdx.x] = (i < n) ? deg[i] : 0;
    __syncthreads();
    for (int st = 128; st > 0; st >>= 1) {
        if (threadIdx.x < st) s[threadIdx.x] += s[threadIdx.x + st];
        __syncthreads();
    }
    if (threadIdx.x == 0) bsum[blockIdx.x] = s[0];
}

// ---- exclusive scan of block sums (single block; nb <= 2048)
__global__ void k_scanb(int* __restrict__ bsum, int nb) {
    __shared__ int s[2048];
    for (int i = threadIdx.x; i < nb; i += blockDim.x) s[i] = bsum[i];
    __syncthreads();
    if (threadIdx.x == 0) {
        int run = 0;
        for (int i = 0; i < nb; i++) { int v = s[i]; s[i] = run; run += v; }
    }
    __syncthreads();
    for (int i = threadIdx.x; i < nb; i += blockDim.x) bsum[i] = s[i];
}

// ---- per-block exclusive scan + block offset -> rowptr, fillpos
__global__ void k_rowptr(const int* __restrict__ deg, const int* __restrict__ boff, int n,
                         int* __restrict__ rowptr, int* __restrict__ fillpos) {
    __shared__ int s[256];
    int tid = threadIdx.x;
    int i = blockIdx.x * 256 + tid;
    int v = (i < n) ? deg[i] : 0;
    s[tid] = v;
    __syncthreads();
    for (int st = 1; st < 256; st <<= 1) {
        int t = (tid >= st) ? s[tid - st] : 0;
        __syncthreads();
        s[tid] += t;
        __syncthreads();
    }
    if (i < n) {
        int excl = s[tid] - v + boff[blockIdx.x];
        rowptr[i] = excl;
        fillpos[i] = excl;
    }
}

// ---- CSR column fill (int atomics on 100k counters)
__global__ void k_fill(const int* __restrict__ src, const int* __restrict__ dst, int n_edges,
                       int* __restrict__ fillpos, int* __restrict__ col) {
    int e = blockIdx.x * blockDim.x + threadIdx.x;
    if (e < n_edges) {
        int pos = atomicAdd(&fillpos[dst[e]], 1);
        col[pos] = src[e];
    }
}

// ---- h = x @ W1 ; dinv = rsqrt(deg+1) ; Hs = h * dinv
__global__ void k_gemm1(const float* __restrict__ x, const float* __restrict__ W1,
                        const int* __restrict__ deg, float* __restrict__ dinv,
                        float* __restrict__ Hs, int n) {
    __shared__ float Ws[N_FEAT * HIDDEN];   // 8 KB
    int tid = threadIdx.x;
    {
        const float4* w4 = (const float4*)W1;
        float4* s4 = (float4*)Ws;
        s4[tid * 2]     = w4[tid * 2];
        s4[tid * 2 + 1] = w4[tid * 2 + 1];
    }
    __syncthreads();
    int i = blockIdx.x * blockDim.x + tid;
    if (i >= n) return;

    float acc[HIDDEN];
#pragma unroll
    for (int o = 0; o < HIDDEN; o++) acc[o] = 0.f;

    const float4* xr = (const float4*)(x + (size_t)i * N_FEAT);
#pragma unroll 8
    for (int k4 = 0; k4 < N_FEAT / 4; k4++) {
        float4 xv = xr[k4];
        const float* w0 = &Ws[(k4 * 4 + 0) * HIDDEN];
        const float* w1 = &Ws[(k4 * 4 + 1) * HIDDEN];
        const float* w2 = &Ws[(k4 * 4 + 2) * HIDDEN];
        const float* w3 = &Ws[(k4 * 4 + 3) * HIDDEN];
#pragma unroll
        for (int o = 0; o < HIDDEN; o++)
            acc[o] += xv.x * w0[o] + xv.y * w1[o] + xv.z * w2[o] + xv.w * w3[o];
    }
    float di = rsqrtf((float)deg[i] + 1.0f);
    dinv[i] = di;
    float4* hout = (float4*)(Hs + (size_t)i * HIDDEN);
#pragma unroll
    for (int q = 0; q < 4; q++) {
        float4 v;
        v.x = acc[q * 4 + 0] * di; v.y = acc[q * 4 + 1] * di;
        v.z = acc[q * 4 + 2] * di; v.w = acc[q * 4 + 3] * di;
        hout[q] = v;
    }
}

// ---- pull-mode aggregation: one wave per dst node, 4 edges x 16 feats in flight.
// LAYER 1: Q[d] = relu(dinv[d]*(sum Hs[nbr] + Hs[d]) + b1) * dinv[d]
// LAYER 2: R[d] = dinv[d]*(sum Q[nbr] + Q[d])
template <int LAYER>
__global__ void k_pull(const float* __restrict__ V, const int* __restrict__ rowptr,
                       const int* __restrict__ deg, const int* __restrict__ col,
                       const float* __restrict__ dinv, const float* __restrict__ b1,
                       float* __restrict__ out, int n) {
    int wid = (blockIdx.x * blockDim.x + threadIdx.x) >> 6;   // node id
    int lane = threadIdx.x & 63;
    if (wid >= n) return;
    int f  = lane & 15;   // feature
    int es = lane >> 4;   // edge slot 0..3
    int start = rowptr[wid];
    int dg = deg[wid];
    float acc = 0.f;
    for (int j = es; j < dg; j += 4) {
        int s = col[start + j];
        acc += V[(size_t)s * HIDDEN + f];
    }
    acc += __shfl_xor(acc, 16, 64);
    acc += __shfl_xor(acc, 32, 64);
    if (lane < 16) {
        float tot = acc + V[(size_t)wid * HIDDEN + f];   // self-loop
        float di = dinv[wid];
        float r;
        if (LAYER == 1) r = fmaxf(di * tot + b1[f], 0.f) * di;  // prescaled for layer 2
        else            r = di * tot;
        out[(size_t)wid * HIDDEN + f] = r;
    }
}

// ---- pooling: S[batch] += R; cnt[batch] += 1 (sorted batch -> LDS buckets)
__global__ void k_pool(const float* __restrict__ R, const int* __restrict__ batch,
                       float* __restrict__ S, float* __restrict__ cnt, int n) {
    __shared__ float ls[8][HIDDEN];
    __shared__ float lc[8];
    int tid = threadIdx.x;
    if (tid < 8) lc[tid] = 0.f;
    if (tid < 8 * HIDDEN) ((float*)ls)[tid] = 0.f;
    __syncthreads();

    int i0 = blockIdx.x * blockDim.x;
    int g0 = batch[i0 < n ? i0 : (n - 1)];
    int i = i0 + tid;
    if (i < n) {
        int g = batch[i];
        const float* r = R + (size_t)i * HIDDEN;
        int off = g - g0;
        if (off >= 0 && off < 8) {
#pragma unroll
            for (int o = 0; o < HIDDEN; o++) atomicAdd(&ls[off][o], r[o]);
            atomicAdd(&lc[off], 1.f);
        } else {
#pragma unroll
            for (int o = 0; o < HIDDEN; o++) atomicAdd(&S[(size_t)g * HIDDEN + o], r[o]);
            atomicAdd(&cnt[g], 1.f);
        }
    }
    __syncthreads();
    if (tid < 8 * HIDDEN) {
        int b = tid >> 4, o = tid & 15;
        int g = g0 + b;
        float v = ls[b][o];
        if (v != 0.f && g < N_GRAPHS) atomicAdd(&S[(size_t)g * HIDDEN + o], v);
    }
    if (tid < 8) {
        int g = g0 + tid;
        float c = lc[tid];
        if (c != 0.f && g < N_GRAPHS) atomicAdd(&cnt[g], c);
    }
}

// ---- out[g][e] = (S[g]/cnt[g]) @ W2 + b2
__global__ void k_out(const float* __restrict__ S, const float* __restrict__ cnt,
                      const float* __restrict__ W2, const float* __restrict__ b2,
                      float* __restrict__ out) {
    int g = blockIdx.x;
    int e = threadIdx.x;
    float c = cnt[g];
    float acc = 0.f;
#pragma unroll
    for (int k = 0; k < HIDDEN; k++) acc += S[g * HIDDEN + k] * W2[k * EMBED + e];
    out[g * EMBED + e] = (c > 0.f) ? (acc / c + b2[e]) : 0.f;
}

extern "C" void kernel_launch(void* const* d_in, const int* in_sizes, int n_in,
                              void* d_out, int out_size, void* d_ws, size_t ws_size,
                              hipStream_t stream) {
    const float* x     = (const float*)d_in[0];
    const int*   ei    = (const int*)  d_in[1];
    const int*   batch = (const int*)  d_in[2];
    const float* W1    = (const float*)d_in[3];
    const float* b1    = (const float*)d_in[4];
    const float* W2    = (const float*)d_in[5];
    const float* b2    = (const float*)d_in[6];
    float* out = (float*)d_out;

    const int n       = in_sizes[2];
    const int n_edges = in_sizes[1] / 2;
    const int* srcp = ei;
    const int* dstp = ei + n_edges;

    const int nb  = (n + 255) / 256;        // 391 node blocks
    const int eb  = (n_edges + 255) / 256;  // edge blocks

    // workspace layout (16B aligned slots)
    float* ws    = (float*)d_ws;
    float* Hs    = ws;                           // n*16 floats (R overwrites it)
    float* Q     = Hs + (size_t)n * HIDDEN;      // n*16 floats
    float* dinv  = Q + (size_t)n * HIDDEN;       // n
    int*   deg   = (int*)(dinv + n);             // n
    int*   rowp  = deg + n;                      // n
    int*   fillp = rowp + n;                     // n
    int*   col   = fillp + n;                    // n_edges
    int*   bsum  = col + n_edges;                // nb (<=2048)
    float* S     = (float*)(bsum + 2048);        // 64*16
    float* cnt   = S + N_GRAPHS * HIDDEN;        // 64

    hipMemsetAsync(deg, 0, (size_t)n * sizeof(int), stream);
    hipMemsetAsync(S, 0, (N_GRAPHS * HIDDEN + N_GRAPHS) * sizeof(float), stream);

    k_deg   <<<eb, 256, 0, stream>>>(dstp, n_edges, deg);
    k_bsum  <<<nb, 256, 0, stream>>>(deg, n, bsum);
    k_scanb <<<1, 256, 0, stream>>>(bsum, nb);
    k_rowptr<<<nb, 256, 0, stream>>>(deg, bsum, n, rowp, fillp);
    k_fill  <<<eb, 256, 0, stream>>>(srcp, dstp, n_edges, fillp, col);
    k_gemm1 <<<nb, 256, 0, stream>>>(x, W1, deg, dinv, Hs, n);

    const int pb = (n * 64 + 255) / 256;    // one wave per node
    k_pull<1><<<pb, 256, 0, stream>>>(Hs, rowp, deg, col, dinv, b1, Q, n);
    k_pull<2><<<pb, 256, 0, stream>>>(Q,  rowp, deg, col, dinv, b1, Hs, n);  // R -> Hs buf

    k_pool  <<<nb, 256, 0, stream>>>(Hs, batch, S, cnt, n);
    k_out   <<<N_GRAPHS, EMBED, 0, stream>>>(S, cnt, W2, b2, out);
}

// Round 4
// 279.032 us; speedup vs baseline: 10.0570x; 1.5530x over previous
//
#include <hip/hip_runtime.h>

#define HIDDEN 16
#define N_FEAT 128
#define EMBED 128
#define N_GRAPHS 64
#define BSH 8              // 256 nodes per bucket
#define MAXB 512           // LDS bound on bucket count (nbuck = 391 here)

// ---- K1: global bucket histogram of dst>>BSH (LDS-first, few global atomics)
__global__ void k_hist(const int* __restrict__ dst, int n_edges, int nbuck,
                       int* __restrict__ ghist) {
    __shared__ int h[MAXB];
    for (int i = threadIdx.x; i < MAXB; i += blockDim.x) h[i] = 0;
    __syncthreads();
    int base = blockIdx.x * blockDim.x * 4;
    for (int j = 0; j < 4; j++) {
        int e = base + j * blockDim.x + threadIdx.x;
        if (e < n_edges) atomicAdd(&h[dst[e] >> BSH], 1);
    }
    __syncthreads();
    for (int b = threadIdx.x; b < nbuck; b += blockDim.x)
        if (h[b]) atomicAdd(&ghist[b], h[b]);
}

// ---- K2: exclusive scan of bucket counts -> gbase; init reservation counters
__global__ void k_scan(const int* __restrict__ ghist, int nbuck,
                       int* __restrict__ gbase, int* __restrict__ gfill) {
    __shared__ int s[MAXB];
    int t = threadIdx.x;                       // 512 threads
    s[t] = (t < nbuck) ? ghist[t] : 0;
    __syncthreads();
    for (int st = 1; st < MAXB; st <<= 1) {
        int v = (t >= st) ? s[t - st] : 0;
        __syncthreads();
        s[t] += v;
        __syncthreads();
    }
    if (t < nbuck) {
        int excl = s[t] - ghist[t];
        gbase[t] = excl;
        gfill[t] = excl;
    }
}

// ---- K3: partition edges into bucket-contiguous ebuf via LDS counting sort
__global__ void __launch_bounds__(1024)
k_part(const int* __restrict__ src, const int* __restrict__ dst,
       int n_edges, int nbuck, int* __restrict__ gfill, uint2* __restrict__ ebuf) {
    __shared__ int hcnt[MAXB];
    __shared__ int hexcl[MAXB];   // inclusive scan; excl = hexcl-hcnt
    __shared__ int hrank[MAXB];
    __shared__ int hbase[MAXB];
    __shared__ uint2 stage[4096];
    int tid = threadIdx.x;
    for (int i = tid; i < MAXB; i += 1024) { hcnt[i] = 0; hrank[i] = 0; }
    __syncthreads();
    int base = blockIdx.x * 4096;
    int cnt = min(4096, n_edges - base);
    int s_[4], d_[4];
#pragma unroll
    for (int j = 0; j < 4; j++) {
        int k = j * 1024 + tid;
        if (k < cnt) {
            s_[j] = src[base + k]; d_[j] = dst[base + k];
            atomicAdd(&hcnt[d_[j] >> BSH], 1);
        }
    }
    __syncthreads();
    if (tid < MAXB) hexcl[tid] = hcnt[tid];
    __syncthreads();
    for (int st = 1; st < MAXB; st <<= 1) {
        int v = 0;
        if (tid < MAXB && tid >= st) v = hexcl[tid - st];
        __syncthreads();
        if (tid < MAXB) hexcl[tid] += v;
        __syncthreads();
    }
    if (tid < nbuck && hcnt[tid] > 0)
        hbase[tid] = atomicAdd(&gfill[tid], hcnt[tid]);
    __syncthreads();
#pragma unroll
    for (int j = 0; j < 4; j++) {
        int k = j * 1024 + tid;
        if (k < cnt) {
            int b = d_[j] >> BSH;
            int r = atomicAdd(&hrank[b], 1);
            stage[hexcl[b] - hcnt[b] + r] = make_uint2((unsigned)s_[j], (unsigned)d_[j]);
        }
    }
    __syncthreads();
    for (int t = tid; t < cnt; t += 1024) {
        uint2 e = stage[t];
        int b = (int)(e.y >> BSH);
        ebuf[hbase[b] + (t - (hexcl[b] - hcnt[b]))] = e;   // per-bucket contiguous runs
    }
}

// ---- K4: per-bucket CSR finalize: deg, rowptr, col (LDS atomics only)
__global__ void __launch_bounds__(1024)
k_csr(const uint2* __restrict__ ebuf, const int* __restrict__ gbase,
      const int* __restrict__ ghist, int n,
      int* __restrict__ deg, int* __restrict__ rowp, int* __restrict__ col) {
    __shared__ int nh[256], nexcl[256], nrank[256];
    int b = blockIdx.x;
    int tid = threadIdx.x;
    int seg0 = gbase[b];
    int cnt = ghist[b];
    int nb0 = b << BSH;
    if (tid < 256) { nh[tid] = 0; nrank[tid] = 0; }
    __syncthreads();
    for (int t = tid; t < cnt; t += 1024)
        atomicAdd(&nh[ebuf[seg0 + t].y - nb0], 1);
    __syncthreads();
    if (tid < 256) nexcl[tid] = nh[tid];
    __syncthreads();
    for (int st = 1; st < 256; st <<= 1) {
        int v = 0;
        if (tid < 256 && tid >= st) v = nexcl[tid - st];
        __syncthreads();
        if (tid < 256) nexcl[tid] += v;
        __syncthreads();
    }
    if (tid < 256) {
        int node = nb0 + tid;
        if (node < n) {
            deg[node]  = nh[tid];
            rowp[node] = seg0 + nexcl[tid] - nh[tid];
        }
    }
    __syncthreads();
    for (int t = tid; t < cnt; t += 1024) {
        uint2 e = ebuf[seg0 + t];
        int ln = (int)e.y - nb0;
        int r = atomicAdd(&nrank[ln], 1);
        col[seg0 + (nexcl[ln] - nh[ln]) + r] = (int)e.x;   // 16KB window, single CU
    }
}

// ---- h = x @ W1 ; dinv = rsqrt(deg+1) ; Hs = h * dinv
__global__ void k_gemm1(const float* __restrict__ x, const float* __restrict__ W1,
                        const int* __restrict__ deg, float* __restrict__ dinv,
                        float* __restrict__ Hs, int n) {
    __shared__ float Ws[N_FEAT * HIDDEN];   // 8 KB
    int tid = threadIdx.x;
    {
        const float4* w4 = (const float4*)W1;
        float4* s4 = (float4*)Ws;
        s4[tid * 2]     = w4[tid * 2];
        s4[tid * 2 + 1] = w4[tid * 2 + 1];
    }
    __syncthreads();
    int i = blockIdx.x * blockDim.x + tid;
    if (i >= n) return;

    float acc[HIDDEN];
#pragma unroll
    for (int o = 0; o < HIDDEN; o++) acc[o] = 0.f;

    const float4* xr = (const float4*)(x + (size_t)i * N_FEAT);
#pragma unroll 8
    for (int k4 = 0; k4 < N_FEAT / 4; k4++) {
        float4 xv = xr[k4];
        const float* w0 = &Ws[(k4 * 4 + 0) * HIDDEN];
        const float* w1 = &Ws[(k4 * 4 + 1) * HIDDEN];
        const float* w2 = &Ws[(k4 * 4 + 2) * HIDDEN];
        const float* w3 = &Ws[(k4 * 4 + 3) * HIDDEN];
#pragma unroll
        for (int o = 0; o < HIDDEN; o++)
            acc[o] += xv.x * w0[o] + xv.y * w1[o] + xv.z * w2[o] + xv.w * w3[o];
    }
    float di = rsqrtf((float)deg[i] + 1.0f);
    dinv[i] = di;
    float4* hout = (float4*)(Hs + (size_t)i * HIDDEN);
#pragma unroll
    for (int q = 0; q < 4; q++) {
        float4 v;
        v.x = acc[q * 4 + 0] * di; v.y = acc[q * 4 + 1] * di;
        v.z = acc[q * 4 + 2] * di; v.w = acc[q * 4 + 3] * di;
        hout[q] = v;
    }
}

// ---- pull-mode aggregation: one wave per dst node, 4 edges x 16 feats in flight.
template <int LAYER>
__global__ void k_pull(const float* __restrict__ V, const int* __restrict__ rowptr,
                       const int* __restrict__ deg, const int* __restrict__ col,
                       const float* __restrict__ dinv, const float* __restrict__ b1,
                       float* __restrict__ out, int n) {
    int wid = (blockIdx.x * blockDim.x + threadIdx.x) >> 6;
    int lane = threadIdx.x & 63;
    if (wid >= n) return;
    int f  = lane & 15;
    int es = lane >> 4;
    int start = rowptr[wid];
    int dg = deg[wid];
    float acc = 0.f;
    for (int j = es; j < dg; j += 4) {
        int s = col[start + j];
        acc += V[(size_t)s * HIDDEN + f];
    }
    acc += __shfl_xor(acc, 16, 64);
    acc += __shfl_xor(acc, 32, 64);
    if (lane < 16) {
        float tot = acc + V[(size_t)wid * HIDDEN + f];   // self-loop
        float di = dinv[wid];
        float r;
        if (LAYER == 1) r = fmaxf(di * tot + b1[f], 0.f) * di;
        else            r = di * tot;
        out[(size_t)wid * HIDDEN + f] = r;
    }
}

// ---- pooling: S[batch] += R; cnt[batch] += 1 (sorted batch -> LDS buckets)
__global__ void k_pool(const float* __restrict__ R, const int* __restrict__ batch,
                       float* __restrict__ S, float* __restrict__ cnt, int n) {
    __shared__ float ls[8][HIDDEN];
    __shared__ float lc[8];
    int tid = threadIdx.x;
    if (tid < 8) lc[tid] = 0.f;
    if (tid < 8 * HIDDEN) ((float*)ls)[tid] = 0.f;
    __syncthreads();

    int i0 = blockIdx.x * blockDim.x;
    int g0 = batch[i0 < n ? i0 : (n - 1)];
    int i = i0 + tid;
    if (i < n) {
        int g = batch[i];
        const float* r = R + (size_t)i * HIDDEN;
        int off = g - g0;
        if (off >= 0 && off < 8) {
#pragma unroll
            for (int o = 0; o < HIDDEN; o++) atomicAdd(&ls[off][o], r[o]);
            atomicAdd(&lc[off], 1.f);
        } else {
#pragma unroll
            for (int o = 0; o < HIDDEN; o++) atomicAdd(&S[(size_t)g * HIDDEN + o], r[o]);
            atomicAdd(&cnt[g], 1.f);
        }
    }
    __syncthreads();
    if (tid < 8 * HIDDEN) {
        int bb = tid >> 4, o = tid & 15;
        int g = g0 + bb;
        float v = ls[bb][o];
        if (v != 0.f && g < N_GRAPHS) atomicAdd(&S[(size_t)g * HIDDEN + o], v);
    }
    if (tid < 8) {
        int g = g0 + tid;
        float c = lc[tid];
        if (c != 0.f && g < N_GRAPHS) atomicAdd(&cnt[g], c);
    }
}

// ---- out[g][e] = (S[g]/cnt[g]) @ W2 + b2
__global__ void k_out(const float* __restrict__ S, const float* __restrict__ cnt,
                      const float* __restrict__ W2, const float* __restrict__ b2,
                      float* __restrict__ out) {
    int g = blockIdx.x;
    int e = threadIdx.x;
    float c = cnt[g];
    float acc = 0.f;
#pragma unroll
    for (int k = 0; k < HIDDEN; k++) acc += S[g * HIDDEN + k] * W2[k * EMBED + e];
    out[g * EMBED + e] = (c > 0.f) ? (acc / c + b2[e]) : 0.f;
}

extern "C" void kernel_launch(void* const* d_in, const int* in_sizes, int n_in,
                              void* d_out, int out_size, void* d_ws, size_t ws_size,
                              hipStream_t stream) {
    const float* x     = (const float*)d_in[0];
    const int*   ei    = (const int*)  d_in[1];
    const int*   batch = (const int*)  d_in[2];
    const float* W1    = (const float*)d_in[3];
    const float* b1    = (const float*)d_in[4];
    const float* W2    = (const float*)d_in[5];
    const float* b2    = (const float*)d_in[6];
    float* out = (float*)d_out;

    const int n       = in_sizes[2];
    const int n_edges = in_sizes[1] / 2;
    const int* srcp = ei;
    const int* dstp = ei + n_edges;
    const int nbuck = (n + 255) >> BSH;      // 391

    // workspace layout
    float* ws    = (float*)d_ws;
    float* Hs    = ws;                           // n*16 (ebuf overlays Hs+Q before gemm1)
    float* Q     = Hs + (size_t)n * HIDDEN;      // n*16
    float* dinv  = Q + (size_t)n * HIDDEN;       // n
    int*   deg   = (int*)(dinv + n);             // n
    int*   rowp  = deg + n;                      // n
    int*   col   = rowp + n;                     // n_edges
    int*   ghist = col + n_edges;                // MAXB
    int*   gbase = ghist + MAXB;                 // MAXB
    int*   gfill = gbase + MAXB;                 // MAXB
    float* S     = (float*)(gfill + MAXB);       // 64*16
    float* cnt   = S + N_GRAPHS * HIDDEN;        // 64
    uint2* ebuf  = (uint2*)Hs;                   // n_edges uint2 == n*32 floats exactly

    hipMemsetAsync(ghist, 0, MAXB * sizeof(int), stream);
    hipMemsetAsync(S, 0, (N_GRAPHS * HIDDEN + N_GRAPHS) * sizeof(float), stream);

    const int pb4k = (n_edges + 4095) / 4096;   // 391
    k_hist<<<pb4k, 1024, 0, stream>>>(dstp, n_edges, nbuck, ghist);
    k_scan<<<1, MAXB, 0, stream>>>(ghist, nbuck, gbase, gfill);
    k_part<<<pb4k, 1024, 0, stream>>>(srcp, dstp, n_edges, nbuck, gfill, ebuf);
    k_csr <<<nbuck, 1024, 0, stream>>>(ebuf, gbase, ghist, n, deg, rowp, col);

    const int nb = (n + 255) / 256;
    k_gemm1<<<nb, 256, 0, stream>>>(x, W1, deg, dinv, Hs, n);

    const int pullb = (n * 64 + 255) / 256;
    k_pull<1><<<pullb, 256, 0, stream>>>(Hs, rowp, deg, col, dinv, b1, Q, n);
    k_pull<2><<<pullb, 256, 0, stream>>>(Q,  rowp, deg, col, dinv, b1, Hs, n);

    k_pool<<<nb, 256, 0, stream>>>(Hs, batch, S, cnt, n);
    k_out <<<N_GRAPHS, EMBED, 0, stream>>>(S, cnt, W2, b2, out);
}